// Round 1
// baseline (555.964 us; speedup 1.0000x reference)
//
#include <hip/hip_runtime.h>
#include <stdint.h>

#define MDIM 8192
#define NDIM 4096
#define KDIM 4096
#define FINAL_SZ (NDIM * KDIM / 4)   // 4,194,304 packed bytes
#define BM 256
#define BN 256
#define BK 64
#define NT (KDIM / BK)               // 64 K-tiles

#define CVT_BLOCKS ((MDIM * KDIM / 8) / 256)     // 16384 blocks, 8 floats/thread
#define UNPACK_BLOCKS ((FINAL_SZ / 8) / 256)     // 2048 blocks, 8 bytes/thread

typedef __attribute__((ext_vector_type(8))) short short8;
typedef __attribute__((ext_vector_type(4))) float floatx4;

typedef const __attribute__((address_space(1))) void global_cv;
typedef __attribute__((address_space(3))) void lds_v;

__device__ __forceinline__ unsigned short f2bf_rne(float f) {
    union { float f; uint32_t u; } a; a.f = f;
    uint32_t u = a.u;
    u += 0x7FFFu + ((u >> 16) & 1u);           // round-to-nearest-even (finite normals)
    return (unsigned short)(u >> 16);
}

// code 0,1,2,3 -> bf16 bits of -1,0,1,2
__device__ __forceinline__ short code2bf(unsigned int c) {
    return (short)((0x40003F800000BF80ull >> (c * 16)) & 0xFFFFull);
}

// ---------- merged prep: x fp32->bf16 AND pw unpack->bf16 W, one dispatch ----------
__global__ void prep_kernel(const float* __restrict__ x, const void* __restrict__ pwv,
                            unsigned short* __restrict__ xb, unsigned short* __restrict__ wb) {
    const int b = blockIdx.x;
    if (b < CVT_BLOCKS) {
        int i = b * 256 + threadIdx.x;
        const float4* xin = (const float4*)x;
        float4 v0 = xin[2 * i];
        float4 v1 = xin[2 * i + 1];
        short8 o;
        o[0] = (short)f2bf_rne(v0.x); o[1] = (short)f2bf_rne(v0.y);
        o[2] = (short)f2bf_rne(v0.z); o[3] = (short)f2bf_rne(v0.w);
        o[4] = (short)f2bf_rne(v1.x); o[5] = (short)f2bf_rne(v1.y);
        o[6] = (short)f2bf_rne(v1.z); o[7] = (short)f2bf_rne(v1.w);
        *(short8*)(xb + (size_t)i * 8) = o;
    } else {
        // layout detect (wave-uniform, globally consistent)
        unsigned int probe = ((const unsigned int*)pwv)[threadIdx.x & 63];
        bool packed = (__ballot(probe > 255u) != 0ull);

        int t = (b - CVT_BLOCKS) * 256 + threadIdx.x;   // 8 packed bytes per thread
        unsigned int lo, hi;
        if (packed) {
            uint2 u = ((const uint2*)pwv)[t];
            lo = u.x; hi = u.y;
        } else {  // int32-widened: one byte value per int
            int4 q0 = ((const int4*)pwv)[2 * t];
            int4 q1 = ((const int4*)pwv)[2 * t + 1];
            lo = (unsigned)(q0.x & 255) | ((unsigned)(q0.y & 255) << 8)
               | ((unsigned)(q0.z & 255) << 16) | ((unsigned)(q0.w & 255) << 24);
            hi = (unsigned)(q1.x & 255) | ((unsigned)(q1.y & 255) << 8)
               | ((unsigned)(q1.z & 255) << 16) | ((unsigned)(q1.w & 255) << 24);
        }
        int j  = t << 3;
        int r  = j >> 12;        // packed row 0..1023
        int ci = j & 4095;       // column (x8 -> 16B-aligned stores)
#pragma unroll
        for (int p = 0; p < 4; ++p) {
            short8 o;
            o[0] = code2bf((lo >> (2 * p)) & 3u);
            o[1] = code2bf((lo >> (8 + 2 * p)) & 3u);
            o[2] = code2bf((lo >> (16 + 2 * p)) & 3u);
            o[3] = code2bf((lo >> (24 + 2 * p)) & 3u);
            o[4] = code2bf((hi >> (2 * p)) & 3u);
            o[5] = code2bf((hi >> (8 + 2 * p)) & 3u);
            o[6] = code2bf((hi >> (16 + 2 * p)) & 3u);
            o[7] = code2bf((hi >> (24 + 2 * p)) & 3u);
            *(short8*)(wb + (((size_t)((p << 10) + r)) << 12) + ci) = o;
        }
    }
}

// ---------- gemm: C = clip((A . B^T) * scale + bias) ----------
// R4: 256x256 8-wave deep-pipelined schedule (T1+T2+T3/T4+T5).
//  - 16x16x32 MFMA (fragment read = 16 rows x 4 swizzled 16B chunks -> conflict-free,
//    vs 4-way conflicts of the 32x32 pattern: SQ_LDS_BANK_CONFLICT was 3.4e7)
//  - double-buffered 128KB LDS; tile t+2's 8 global_load_lds burst-issued at the
//    boundary after tile t's last read barrier (write-after-read safe), so the
//    steady-state wait is vmcnt(8), never a full drain; every load has ~4 phases
//    of latency slack.
//  - 4 phases/K-tile, one C-quadrant each (16 MFMA), register fragment reuse
//    (24 x ds_read_b128 per tile per wave = minimum), setprio around MFMA.
//  - raw s_barrier + asm waitcnt (no __syncthreads -> no compiler-forced drain).
__device__ __forceinline__ void block_bar() {
    asm volatile("" ::: "memory");
    __builtin_amdgcn_s_barrier();
    asm volatile("" ::: "memory");
}

__global__ __launch_bounds__(512, 2) void gemm_ternary(
    const unsigned short* __restrict__ A,
    const unsigned short* __restrict__ B,
    const float* __restrict__ scale,
    const float* __restrict__ bias,
    float* __restrict__ C) {
    __shared__ __align__(16) unsigned short lA[2][BM * BK];  // 2 x 32 KiB
    __shared__ __align__(16) unsigned short lB[2][BN * BK];  // 2 x 32 KiB

    const int tid  = threadIdx.x;
    const int lane = tid & 63;
    const int wave = tid >> 6;       // 0..7
    const int wm   = wave >> 2;      // 0..1  (M half: 128 rows)
    const int wn   = wave & 3;       // 0..3  (N quarter: 64 cols)
    const int l15  = lane & 15;
    const int lq   = lane >> 4;      // 0..3
    const int lx   = lane & 7;

    // XCD-aware bijective swizzle: 512 wgs = 8 XCDs x 64
    const int bid = blockIdx.x;
    const int wg  = ((bid & 7) << 6) | (bid >> 3);
    const int m0  = (wg >> 4) * BM;  // 32 M-tiles
    const int n0  = (wg & 15) * BN;  // 16 N-tiles

    // staging: 8 rounds/wave/K-tile (4 A + 4 B), 1KB per global_load_lds.
    // LDS dest linear; global source pre-swizzled: chunk ^= (row & 7).
    const char* gA[4];
    const char* gB[4];
    int lOff[4];
#pragma unroll
    for (int r = 0; r < 4; ++r) {
        int rowr = r * 64 + wave * 8 + (lane >> 3);
        int cg   = (lane & 7) ^ ((lane >> 3) & 7);   // rowr & 7 == (lane>>3) & 7
        gA[r] = (const char*)(A + (size_t)(m0 + rowr) * KDIM + cg * 8);
        gB[r] = (const char*)(B + (size_t)(n0 + rowr) * KDIM + cg * 8);
        lOff[r] = (r * 64 + wave * 8) * BK;          // wave-uniform LDS element offset
    }

    // fragment-read swizzled chunk offsets (elements); frag row & 7 == lane & 7
    int cOff[2];
#pragma unroll
    for (int ks = 0; ks < 2; ++ks)
        cOff[ks] = ((((ks << 2) + lq) ^ lx) << 3);

    floatx4 acc[8][4];
#pragma unroll
    for (int i = 0; i < 8; ++i)
#pragma unroll
        for (int j = 0; j < 4; ++j)
            acc[i][j] = (floatx4)(0.f);

#define ISSUE8(cbuf)                                                              \
    {                                                                             \
        _Pragma("unroll") for (int r = 0; r < 4; ++r) {                           \
            __builtin_amdgcn_global_load_lds((global_cv*)gA[r],                   \
                (lds_v*)(&lA[(cbuf)][0] + lOff[r]), 16, 0, 0);                    \
            gA[r] += BK * 2;                                                      \
        }                                                                         \
        _Pragma("unroll") for (int r = 0; r < 4; ++r) {                           \
            __builtin_amdgcn_global_load_lds((global_cv*)gB[r],                   \
                (lds_v*)(&lB[(cbuf)][0] + lOff[r]), 16, 0, 0);                    \
            gB[r] += BK * 2;                                                      \
        }                                                                         \
    }

    // prologue: tiles 0 and 1 in flight; wait tile 0 (8 younger stay in flight)
    ISSUE8(0)
    ISSUE8(1)
    asm volatile("s_waitcnt vmcnt(8)" ::: "memory");
    __builtin_amdgcn_s_barrier();
    asm volatile("" ::: "memory");

    for (int t = 0; t < NT; ++t) {
        const unsigned short* LA = &lA[t & 1][0];
        const unsigned short* LB = &lB[t & 1][0];
        short8 a0[4][2], a1[4][2], b0[2][2], b1[2][2];

        // ---- phase 0: read A-h0 (8) + B-v0 (4); MFMA q(lo,lo)
#pragma unroll
        for (int i = 0; i < 4; ++i)
#pragma unroll
            for (int ks = 0; ks < 2; ++ks)
                a0[i][ks] = *(const short8*)(LA + (wm * 128 + i * 16 + l15) * BK + cOff[ks]);
#pragma unroll
        for (int j = 0; j < 2; ++j)
#pragma unroll
            for (int ks = 0; ks < 2; ++ks)
                b0[j][ks] = *(const short8*)(LB + (wn * 64 + j * 16 + l15) * BK + cOff[ks]);
        block_bar();
        __builtin_amdgcn_s_setprio(1);
#pragma unroll
        for (int i = 0; i < 4; ++i)
#pragma unroll
            for (int j = 0; j < 2; ++j)
#pragma unroll
                for (int ks = 0; ks < 2; ++ks)
                    acc[i][j] = __builtin_amdgcn_mfma_f32_16x16x32_bf16(
                        a0[i][ks], b0[j][ks], acc[i][j], 0, 0, 0);
        __builtin_amdgcn_s_setprio(0);
        block_bar();

        // ---- phase 1: read B-v1 (4); MFMA q(lo,hi)
#pragma unroll
        for (int j = 0; j < 2; ++j)
#pragma unroll
            for (int ks = 0; ks < 2; ++ks)
                b1[j][ks] = *(const short8*)(LB + (wn * 64 + 32 + j * 16 + l15) * BK + cOff[ks]);
        block_bar();
        __builtin_amdgcn_s_setprio(1);
#pragma unroll
        for (int i = 0; i < 4; ++i)
#pragma unroll
            for (int j = 0; j < 2; ++j)
#pragma unroll
                for (int ks = 0; ks < 2; ++ks)
                    acc[i][2 + j] = __builtin_amdgcn_mfma_f32_16x16x32_bf16(
                        a0[i][ks], b1[j][ks], acc[i][2 + j], 0, 0, 0);
        __builtin_amdgcn_s_setprio(0);
        block_bar();

        // ---- phase 2: read A-h1 (8); MFMA q(hi,hi)
#pragma unroll
        for (int i = 0; i < 4; ++i)
#pragma unroll
            for (int ks = 0; ks < 2; ++ks)
                a1[i][ks] = *(const short8*)(LA + (wm * 128 + 64 + i * 16 + l15) * BK + cOff[ks]);
        block_bar();
        __builtin_amdgcn_s_setprio(1);
#pragma unroll
        for (int i = 0; i < 4; ++i)
#pragma unroll
            for (int j = 0; j < 2; ++j)
#pragma unroll
                for (int ks = 0; ks < 2; ++ks)
                    acc[4 + i][2 + j] = __builtin_amdgcn_mfma_f32_16x16x32_bf16(
                        a1[i][ks], b1[j][ks], acc[4 + i][2 + j], 0, 0, 0);
        __builtin_amdgcn_s_setprio(0);
        block_bar();

        // ---- phase 3: no reads (b0 reused from regs); MFMA q(hi,lo)
        __builtin_amdgcn_s_setprio(1);
#pragma unroll
        for (int i = 0; i < 4; ++i)
#pragma unroll
            for (int j = 0; j < 2; ++j)
#pragma unroll
                for (int ks = 0; ks < 2; ++ks)
                    acc[4 + i][j] = __builtin_amdgcn_mfma_f32_16x16x32_bf16(
                        a1[i][ks], b0[j][ks], acc[4 + i][j], 0, 0, 0);
        __builtin_amdgcn_s_setprio(0);
        block_bar();   // all reads of buf[t&1] complete across the block

        // ---- boundary: burst-issue tile t+2 into the buffer just freed,
        //      then counted wait for tile t+1 (8 newest stay in flight)
        if (t + 2 < NT) {
            ISSUE8(t & 1)
            asm volatile("s_waitcnt vmcnt(8)" ::: "memory");
            __builtin_amdgcn_s_barrier();
            asm volatile("" ::: "memory");
        } else if (t + 1 < NT) {
            asm volatile("s_waitcnt vmcnt(0)" ::: "memory");
            __builtin_amdgcn_s_barrier();
            asm volatile("" ::: "memory");
        }
    }
#undef ISSUE8

    // epilogue: 16x16x32 C/D layout (m89-verified): n = lane&15, m = (lane>>4)*4 + reg
    float sc[4], bi[4];
#pragma unroll
    for (int nj = 0; nj < 4; ++nj) {
        int n  = n0 + wn * 64 + nj * 16 + l15;
        sc[nj] = scale[n];
        bi[nj] = bias[n];
    }
#pragma unroll
    for (int mi = 0; mi < 8; ++mi) {
#pragma unroll
        for (int r = 0; r < 4; ++r) {
            int m = m0 + wm * 128 + mi * 16 + lq * 4 + r;
            float* Crow = C + (size_t)m * NDIM + n0 + wn * 64 + l15;
#pragma unroll
            for (int nj = 0; nj < 4; ++nj) {
                float v = acc[mi][nj][r] * sc[nj] + bi[nj];
                v = fminf(100.f, fmaxf(-100.f, v));
                Crow[nj * 16] = v;
            }
        }
    }
}

extern "C" void kernel_launch(void* const* d_in, const int* in_sizes, int n_in,
                              void* d_out, int out_size, void* d_ws, size_t ws_size,
                              hipStream_t stream) {
    const float* x  = (const float*)d_in[0];
    const void*  pw = d_in[1];                 // packed uint8 OR int32-widened; device-detected
    const float* scale = (const float*)d_in[2];
    const float* bias  = (const float*)d_in[3];
    float* out = (float*)d_out;

    // workspace: [0, 64MiB) x_bf16 | [64MiB, 96MiB) w_bf16
    unsigned short* xb = (unsigned short*)d_ws;
    unsigned short* wb = xb + (size_t)MDIM * KDIM;

    prep_kernel<<<CVT_BLOCKS + UNPACK_BLOCKS, 256, 0, stream>>>(x, pw, xb, wb);

    gemm_ternary<<<dim3((MDIM / BM) * (NDIM / BN)), 512, 0, stream>>>(xb, wb, scale, bias, out);
}

// Round 3
// 484.774 us; speedup vs baseline: 1.1469x; 1.1469x over previous
//
#include <hip/hip_runtime.h>
#include <stdint.h>

#define MDIM 8192
#define NDIM 4096
#define KDIM 4096
#define FINAL_SZ (NDIM * KDIM / 4)   // 4,194,304 packed bytes
#define BM 256
#define BN 256
#define BK 64
#define NT (KDIM / BK)               // 64 K-tiles

#define CVT_BLOCKS ((MDIM * KDIM / 8) / 256)     // 16384 blocks, 8 floats/thread
#define UNPACK_BLOCKS ((FINAL_SZ / 8) / 256)     // 2048 blocks, 8 bytes/thread

typedef __attribute__((ext_vector_type(8))) short short8;
typedef __attribute__((ext_vector_type(4))) float floatx4;

typedef const __attribute__((address_space(1))) void global_cv;
typedef __attribute__((address_space(3))) void lds_v;

__device__ __forceinline__ unsigned short f2bf_rne(float f) {
    union { float f; uint32_t u; } a; a.f = f;
    uint32_t u = a.u;
    u += 0x7FFFu + ((u >> 16) & 1u);           // round-to-nearest-even (finite normals)
    return (unsigned short)(u >> 16);
}

// code 0,1,2,3 -> bf16 bits of -1,0,1,2
__device__ __forceinline__ short code2bf(unsigned int c) {
    return (short)((0x40003F800000BF80ull >> (c * 16)) & 0xFFFFull);
}

// ---------- merged prep: x fp32->bf16 AND pw unpack->bf16 W, one dispatch ----------
__global__ void prep_kernel(const float* __restrict__ x, const void* __restrict__ pwv,
                            unsigned short* __restrict__ xb, unsigned short* __restrict__ wb) {
    const int b = blockIdx.x;
    if (b < CVT_BLOCKS) {
        int i = b * 256 + threadIdx.x;
        const float4* xin = (const float4*)x;
        float4 v0 = xin[2 * i];
        float4 v1 = xin[2 * i + 1];
        short8 o;
        o[0] = (short)f2bf_rne(v0.x); o[1] = (short)f2bf_rne(v0.y);
        o[2] = (short)f2bf_rne(v0.z); o[3] = (short)f2bf_rne(v0.w);
        o[4] = (short)f2bf_rne(v1.x); o[5] = (short)f2bf_rne(v1.y);
        o[6] = (short)f2bf_rne(v1.z); o[7] = (short)f2bf_rne(v1.w);
        *(short8*)(xb + (size_t)i * 8) = o;
    } else {
        // layout detect (wave-uniform, globally consistent)
        unsigned int probe = ((const unsigned int*)pwv)[threadIdx.x & 63];
        bool packed = (__ballot(probe > 255u) != 0ull);

        int t = (b - CVT_BLOCKS) * 256 + threadIdx.x;   // 8 packed bytes per thread
        unsigned int lo, hi;
        if (packed) {
            uint2 u = ((const uint2*)pwv)[t];
            lo = u.x; hi = u.y;
        } else {  // int32-widened: one byte value per int
            int4 q0 = ((const int4*)pwv)[2 * t];
            int4 q1 = ((const int4*)pwv)[2 * t + 1];
            lo = (unsigned)(q0.x & 255) | ((unsigned)(q0.y & 255) << 8)
               | ((unsigned)(q0.z & 255) << 16) | ((unsigned)(q0.w & 255) << 24);
            hi = (unsigned)(q1.x & 255) | ((unsigned)(q1.y & 255) << 8)
               | ((unsigned)(q1.z & 255) << 16) | ((unsigned)(q1.w & 255) << 24);
        }
        int j  = t << 3;
        int r  = j >> 12;        // packed row 0..1023
        int ci = j & 4095;       // column (x8 -> 16B-aligned stores)
#pragma unroll
        for (int p = 0; p < 4; ++p) {
            short8 o;
            o[0] = code2bf((lo >> (2 * p)) & 3u);
            o[1] = code2bf((lo >> (8 + 2 * p)) & 3u);
            o[2] = code2bf((lo >> (16 + 2 * p)) & 3u);
            o[3] = code2bf((lo >> (24 + 2 * p)) & 3u);
            o[4] = code2bf((hi >> (2 * p)) & 3u);
            o[5] = code2bf((hi >> (8 + 2 * p)) & 3u);
            o[6] = code2bf((hi >> (16 + 2 * p)) & 3u);
            o[7] = code2bf((hi >> (24 + 2 * p)) & 3u);
            *(short8*)(wb + (((size_t)((p << 10) + r)) << 12) + ci) = o;
        }
    }
}

// ---------- gemm: C = clip((A . B^T) * scale + bias) ----------
// R6 == R5 resubmitted (round 2 failed on container acquisition, no kernel signal).
// 256x256 8-wave 4-phase skeleton (conflict-free 16x16 frags, XOR swizzle,
// setprio, raw barriers) with the FINE STAGE INTERLEAVE (m196/m218 lever):
//  - 8 loads/tile split into dependency-aligned groups; 2 issued per phase for
//    tile t+1 into the other buffer (WAR-safe: last read of that buffer is >=2
//    barriers upstream).
//  - counted vmcnt(4) at ends of P0/P1/P3 (never 0 in main loop); each wait's
//    target loads were issued >= 2 phases earlier; max 8 loads in flight.
//  - cross-wave landing visibility: every vmcnt is followed by the phase barrier.
#define VWAIT4 asm volatile("s_waitcnt vmcnt(4)" ::: "memory")
#define VWAIT2 asm volatile("s_waitcnt vmcnt(2)" ::: "memory")
#define VWAIT0 asm volatile("s_waitcnt vmcnt(0)" ::: "memory")
#define BARX() do { asm volatile("" ::: "memory"); __builtin_amdgcn_s_barrier(); asm volatile("" ::: "memory"); } while (0)

__global__ __launch_bounds__(512, 2) void gemm_ternary(
    const unsigned short* __restrict__ A,
    const unsigned short* __restrict__ B,
    const float* __restrict__ scale,
    const float* __restrict__ bias,
    float* __restrict__ C) {
    __shared__ __align__(16) unsigned short lA[2][BM * BK];  // 2 x 32 KiB
    __shared__ __align__(16) unsigned short lB[2][BN * BK];  // 2 x 32 KiB

    const int tid  = threadIdx.x;
    const int lane = tid & 63;
    const int wave = tid >> 6;       // 0..7
    const int wm   = wave >> 2;      // 0..1  (M half: 128 rows)
    const int wn   = wave & 3;       // 0..3  (N quarter: 64 cols)
    const int l15  = lane & 15;
    const int lq   = lane >> 4;      // 0..3
    const int lx   = lane & 7;

    // XCD-aware bijective swizzle: 512 wgs = 8 XCDs x 64
    const int bid = blockIdx.x;
    const int wg  = ((bid & 7) << 6) | (bid >> 3);
    const int m0  = (wg >> 4) * BM;  // 32 M-tiles
    const int n0  = (wg & 15) * BN;  // 16 N-tiles

    // ---- staging groups (each = one global_load_lds/wave = 64 rows blockwide) ----
    // A group g covers rows: g0:0-63 (P0,wm0) g1:128-191 (P0,wm1)
    //                        g2:64-127 (P2,wm0) g3:192-255 (P2,wm1)
    // B group g covers the b0-rows (bit5=0) for g<2, b1-rows (bit5=1) for g>=2:
    //   g0:{0-31,64-95} g1:{128-159,192-223}  (P0/P1 consumers j=0,1 lo)
    //   g2:{32-63,96-127} g3:{160-191,224-255} (P1 consumers hi)
    const int lr = lane >> 3;          // 0..7 rows within a wave's 8-row slice
    const int cg = (lane & 7) ^ lr;    // pre-swizzled global 16B chunk (row&7 == lr)
    const char* gA[4];
    const char* gB[4];
    int offA[4], offB[4];
#pragma unroll
    for (int g = 0; g < 4; ++g) {
        const int ab = ((g & 1) << 7) + ((g >> 1) << 6) + wave * 8;  // 0,128,64,192 + wave*8
        offA[g] = ab * BK;
        gA[g] = (const char*)(A + (size_t)(m0 + ab + lr) * KDIM + cg * 8);
        const int bb = ((g & 1) << 7) + ((g >> 1) << 5)
                     + ((wave >> 2) << 6) + ((wave & 3) << 3);
        offB[g] = bb * BK;
        gB[g] = (const char*)(B + (size_t)(n0 + bb + lr) * KDIM + cg * 8);
    }

    // fragment-read swizzled chunk offsets (elements); frag row & 7 == lane & 7
    int cOff[2];
#pragma unroll
    for (int ks = 0; ks < 2; ++ks)
        cOff[ks] = ((((ks << 2) + lq) ^ lx) << 3);

    floatx4 acc[8][4];
#pragma unroll
    for (int i = 0; i < 8; ++i)
#pragma unroll
        for (int j = 0; j < 4; ++j)
            acc[i][j] = (floatx4)(0.f);

#define SGA(g, sb) do {                                                          \
        __builtin_amdgcn_global_load_lds((global_cv*)gA[g],                      \
            (lds_v*)(&lA[sb][0] + offA[g]), 16, 0, 0);                           \
        gA[g] += BK * 2; } while (0)
#define SGB(g, sb) do {                                                          \
        __builtin_amdgcn_global_load_lds((global_cv*)gB[g],                      \
            (lds_v*)(&lB[sb][0] + offB[g]), 16, 0, 0);                           \
        gB[g] += BK * 2; } while (0)

#define MFMA_Q(AF, BF, MI0, NJ0)                                                 \
    __builtin_amdgcn_s_setprio(1);                                               \
    _Pragma("unroll") for (int i = 0; i < 4; ++i)                                \
    _Pragma("unroll") for (int j = 0; j < 2; ++j)                                \
    _Pragma("unroll") for (int ks = 0; ks < 2; ++ks)                             \
        acc[(MI0) + i][(NJ0) + j] = __builtin_amdgcn_mfma_f32_16x16x32_bf16(     \
            AF[i][ks], BF[j][ks], acc[(MI0) + i][(NJ0) + j], 0, 0, 0);           \
    __builtin_amdgcn_s_setprio(0)

// one K-tile: 4 phases x {ds_reads; stage 2; bar; MFMA quadrant; [wait]; bar}
#define TILE_ITER(bufv, DOSTAGE, W0STMT, W1STMT, W3STMT)                         \
  {                                                                              \
    const unsigned short* LA = &lA[bufv][0];                                     \
    const unsigned short* LB = &lB[bufv][0];                                     \
    const int sb = (bufv) ^ 1; (void)sb;                                         \
    short8 a0[4][2], a1[4][2], b0[2][2], b1[2][2];                               \
    /* P0: a0,b0 reads; stage A-lo groups of t+1; MFMA q(lo,lo) */               \
    _Pragma("unroll") for (int i = 0; i < 4; ++i)                                \
    _Pragma("unroll") for (int ks = 0; ks < 2; ++ks)                             \
        a0[i][ks] = *(const short8*)(LA + (wm * 128 + i * 16 + l15) * BK + cOff[ks]); \
    _Pragma("unroll") for (int j = 0; j < 2; ++j)                                \
    _Pragma("unroll") for (int ks = 0; ks < 2; ++ks)                             \
        b0[j][ks] = *(const short8*)(LB + (wn * 64 + j * 16 + l15) * BK + cOff[ks]);  \
    if (DOSTAGE) { SGA(0, sb); SGA(1, sb); }                                     \
    BARX();                                                                      \
    MFMA_Q(a0, b0, 0, 0);                                                        \
    W0STMT;                                                                      \
    BARX();                                                                      \
    /* P1: b1 reads (needs B g2,g3); stage B-lo groups; MFMA q(lo,hi) */         \
    _Pragma("unroll") for (int j = 0; j < 2; ++j)                                \
    _Pragma("unroll") for (int ks = 0; ks < 2; ++ks)                             \
        b1[j][ks] = *(const short8*)(LB + (wn * 64 + 32 + j * 16 + l15) * BK + cOff[ks]); \
    if (DOSTAGE) { SGB(0, sb); SGB(1, sb); }                                     \
    BARX();                                                                      \
    MFMA_Q(a0, b1, 0, 2);                                                        \
    W1STMT;                                                                      \
    BARX();                                                                      \
    /* P2: a1 reads (needs A g2,g3); stage B-hi groups; MFMA q(hi,hi) */         \
    _Pragma("unroll") for (int i = 0; i < 4; ++i)                                \
    _Pragma("unroll") for (int ks = 0; ks < 2; ++ks)                             \
        a1[i][ks] = *(const short8*)(LA + (wm * 128 + 64 + i * 16 + l15) * BK + cOff[ks]); \
    if (DOSTAGE) { SGB(2, sb); SGB(3, sb); }                                     \
    BARX();                                                                      \
    MFMA_Q(a1, b1, 4, 2);                                                        \
    BARX();                                                                      \
    /* P3: no reads (b0 reused); stage A-hi groups; MFMA q(hi,lo) */             \
    if (DOSTAGE) { SGA(2, sb); SGA(3, sb); }                                     \
    BARX();                                                                      \
    MFMA_Q(a1, b0, 4, 0);                                                        \
    W3STMT;                                                                      \
    BARX();                                                                      \
  }

    // prologue: tile 0, oldest-first in dependency order; keep 4 youngest in flight
    SGA(0, 0); SGA(1, 0); SGB(0, 0); SGB(1, 0);
    SGB(2, 0); SGB(3, 0); SGA(2, 0); SGA(3, 0);
    VWAIT4;
    BARX();

    for (int t = 0; t < NT - 1; ++t) {
        TILE_ITER(t & 1, 1, VWAIT4, VWAIT4, VWAIT4)
    }
    // peeled final tile (NT-1 = 63, buf 1): no staging; drain with counted waits
    TILE_ITER(1, 0, VWAIT2, VWAIT0, (void)0)

#undef TILE_ITER
#undef MFMA_Q
#undef SGA
#undef SGB

    // epilogue: 16x16x32 C/D layout (m89-verified): n = lane&15, m = (lane>>4)*4 + reg
    float sc[4], bi[4];
#pragma unroll
    for (int nj = 0; nj < 4; ++nj) {
        int n  = n0 + wn * 64 + nj * 16 + l15;
        sc[nj] = scale[n];
        bi[nj] = bias[n];
    }
#pragma unroll
    for (int mi = 0; mi < 8; ++mi) {
#pragma unroll
        for (int r = 0; r < 4; ++r) {
            int m = m0 + wm * 128 + mi * 16 + lq * 4 + r;
            float* Crow = C + (size_t)m * NDIM + n0 + wn * 64 + l15;
#pragma unroll
            for (int nj = 0; nj < 4; ++nj) {
                float v = acc[mi][nj][r] * sc[nj] + bi[nj];
                v = fminf(100.f, fmaxf(-100.f, v));
                Crow[nj * 16] = v;
            }
        }
    }
}

extern "C" void kernel_launch(void* const* d_in, const int* in_sizes, int n_in,
                              void* d_out, int out_size, void* d_ws, size_t ws_size,
                              hipStream_t stream) {
    const float* x  = (const float*)d_in[0];
    const void*  pw = d_in[1];                 // packed uint8 OR int32-widened; device-detected
    const float* scale = (const float*)d_in[2];
    const float* bias  = (const float*)d_in[3];
    float* out = (float*)d_out;

    // workspace: [0, 64MiB) x_bf16 | [64MiB, 96MiB) w_bf16
    unsigned short* xb = (unsigned short*)d_ws;
    unsigned short* wb = xb + (size_t)MDIM * KDIM;

    prep_kernel<<<CVT_BLOCKS + UNPACK_BLOCKS, 256, 0, stream>>>(x, pw, xb, wb);

    gemm_ternary<<<dim3((MDIM / BM) * (NDIM / BN)), 512, 0, stream>>>(xb, wb, scale, bias, out);
}